// Round 4
// baseline (135.577 us; speedup 1.0000x reference)
//
#include <hip/hip_runtime.h>
#include <math.h>

constexpr int LL   = 384;
constexpr int FF   = 128;
constexpr int NH   = 12;
constexpr int HQK  = 384;
constexpr int HV   = 384;
constexpr int HP3  = 288;
constexpr int NPT  = 96;
constexpr int CC   = 64;
constexpr int DOUT = 1824;

// ---------------- K1a: all six projections as one tiled GEMM ----------------
__global__ void __launch_bounds__(256) k1a_gemm(
    const float* __restrict__ x,
    const float* __restrict__ Wq, const float* __restrict__ Wk, const float* __restrict__ Wv,
    const float* __restrict__ Wqp, const float* __restrict__ Wkp, const float* __restrict__ Wvp,
    float* __restrict__ qb, float* __restrict__ kb, float* __restrict__ vb,
    float* __restrict__ qp, float* __restrict__ kp, float* __restrict__ vp) {
    const int ct = blockIdx.x;       // 0..62
    const int rt = blockIdx.y;       // 0..5
    const int tid = threadIdx.x;
    __shared__ float xs[64 * 132];

    const float* W; float* O; int ld, cb;
    if (ct < 12)      { W = Wq;  O = qb; ld = 384; cb = ct * 32; }
    else if (ct < 24) { W = Wk;  O = kb; ld = 384; cb = (ct - 12) * 32; }
    else if (ct < 36) { W = Wv;  O = vb; ld = 384; cb = (ct - 24) * 32; }
    else if (ct < 45) { W = Wqp; O = qp; ld = 288; cb = (ct - 36) * 32; }
    else if (ct < 54) { W = Wkp; O = kp; ld = 288; cb = (ct - 45) * 32; }
    else              { W = Wvp; O = vp; ld = 288; cb = (ct - 54) * 32; }
    const int r0 = rt * 64;

    const float4* xsrc = (const float4*)(x + (size_t)r0 * FF);
#pragma unroll
    for (int k = 0; k < 8; ++k) {
        int idx = tid + k * 256;
        float4 v = xsrc[idx];
        int row = idx >> 5, c4 = (idx & 31) * 4;
        float* d = &xs[row * 132 + c4];
        d[0] = v.x; d[1] = v.y; d[2] = v.z; d[3] = v.w;
    }
    __syncthreads();

    const int cq = (tid & 7) * 4;
    const int rr = (tid >> 3) * 2;
    const float* Wp = W + cb + cq;
    const float* xr0 = &xs[rr * 132];
    const float* xr1 = &xs[(rr + 1) * 132];
    float a00=0,a01=0,a02=0,a03=0, a10=0,a11=0,a12=0,a13=0;
#pragma unroll 4
    for (int f = 0; f < FF; ++f) {
        const float4 w = *(const float4*)(Wp + (size_t)f * ld);
        float xa = xr0[f], xb = xr1[f];
        a00 = fmaf(xa, w.x, a00); a01 = fmaf(xa, w.y, a01);
        a02 = fmaf(xa, w.z, a02); a03 = fmaf(xa, w.w, a03);
        a10 = fmaf(xb, w.x, a10); a11 = fmaf(xb, w.y, a11);
        a12 = fmaf(xb, w.z, a12); a13 = fmaf(xb, w.w, a13);
    }
    float* o0 = O + (size_t)(r0 + rr) * ld + cb + cq;
    float* o1 = o0 + ld;
    o0[0]=a00; o0[1]=a01; o0[2]=a02; o0[3]=a03;
    o1[0]=a10; o1[1]=a11; o1[2]=a12; o1[3]=a13;
}

// ---------------- K1b: rigid transforms in place, norms, gamma ----------------
__global__ void __launch_bounds__(128) k1b_derived(
    const float* __restrict__ R, const float* __restrict__ t,
    float* __restrict__ qp, float* __restrict__ kp, float* __restrict__ vp,
    float* __restrict__ qnb, float* __restrict__ knb,
    const float* __restrict__ spc, float* __restrict__ gam) {
    const int i = blockIdx.x, tid = threadIdx.x;
    __shared__ float nq[NPT], nk[NPT];
    const float r00=R[i*9+0], r01=R[i*9+1], r02=R[i*9+2];
    const float r10=R[i*9+3], r11=R[i*9+4], r12=R[i*9+5];
    const float r20=R[i*9+6], r21=R[i*9+7], r22=R[i*9+8];
    const float t0=t[i*3+0], t1=t[i*3+1], t2=t[i*3+2];

    if (tid < NPT) {
        size_t base = (size_t)i * HP3 + tid * 3;
        {
            float l0=qp[base], l1=qp[base+1], l2=qp[base+2];
            float g0=r00*l0+r01*l1+r02*l2+t0;
            float g1=r10*l0+r11*l1+r12*l2+t1;
            float g2=r20*l0+r21*l1+r22*l2+t2;
            qp[base]=g0; qp[base+1]=g1; qp[base+2]=g2;
            nq[tid]=g0*g0+g1*g1+g2*g2;
        }
        {
            float l0=kp[base], l1=kp[base+1], l2=kp[base+2];
            float g0=r00*l0+r01*l1+r02*l2+t0;
            float g1=r10*l0+r11*l1+r12*l2+t1;
            float g2=r20*l0+r21*l1+r22*l2+t2;
            kp[base]=g0; kp[base+1]=g1; kp[base+2]=g2;
            nk[tid]=g0*g0+g1*g1+g2*g2;
        }
        {
            float l0=vp[base], l1=vp[base+1], l2=vp[base+2];
            float g0=r00*l0+r01*l1+r02*l2+t0;
            float g1=r10*l0+r11*l1+r12*l2+t1;
            float g2=r20*l0+r21*l1+r22*l2+t2;
            vp[base]=g0; vp[base+1]=g1; vp[base+2]=g2;
        }
    }
    __syncthreads();
    if (tid < NH) {
        float sq=0.f, sk=0.f;
#pragma unroll
        for (int p=0;p<8;++p){ sq+=nq[tid*8+p]; sk+=nk[tid*8+p]; }
        qnb[(size_t)i*NH+tid]=sq;
        knb[(size_t)i*NH+tid]=sk;
    }
    if (i == 0 && tid < NH) gam[tid] = log1pf(expf(spc[tid]));
}

// ---------------- K3: node+spatial logits as rank-58 bilinear GEMM ----------------
// grid (6 it, 6 jt, 12 h), 256 thr, 64x64 tile, thread = 4x4.
__global__ void __launch_bounds__(256) k3_node(
    const float* __restrict__ qb, const float* __restrict__ kb,
    const float* __restrict__ qp, const float* __restrict__ kp,
    const float* __restrict__ qnb, const float* __restrict__ knb,
    const float* __restrict__ gam, float* __restrict__ lgN) {
    const int it = blockIdx.x, jt = blockIdx.y, h = blockIdx.z;
    const int tid = threadIdx.x;
    __shared__ float As[64 * 60];
    __shared__ float Bs[64 * 60];
    const float g = gam[h];
    const float s3 = 0.5773502691896258f;
    const float c1 = s3 * 0.17677669529663687f;   // s3/sqrt(32)
    const float c2 = s3 * g * (1.f / 6.f);        // +2*cross coefficient
    const float c3 = -s3 * g * (1.f / 12.f);      // qn/kn coefficient
    const int i0 = it * 64, j0 = jt * 64;

    for (int idx = tid; idx < 2048; idx += 256) {
        int r = idx >> 5, c = idx & 31;
        As[r*60 + c] = qb[(size_t)(i0 + r) * HQK + h*32 + c];
        Bs[r*60 + c] = kb[(size_t)(j0 + r) * HQK + h*32 + c] * c1;
    }
    for (int idx = tid; idx < 2048; idx += 256) {
        int r = idx >> 5, c = idx & 31;
        if (c < 24) {
            As[r*60 + 32 + c] = qp[(size_t)(i0+r) * HP3 + h*24 + c];
            Bs[r*60 + 32 + c] = kp[(size_t)(j0+r) * HP3 + h*24 + c] * c2;
        } else if (c == 24) {
            As[r*60 + 56] = qnb[(size_t)(i0+r) * NH + h];
            As[r*60 + 57] = 1.f;
            As[r*60 + 58] = 0.f; As[r*60 + 59] = 0.f;
            Bs[r*60 + 56] = c3;
            Bs[r*60 + 57] = c3 * knb[(size_t)(j0+r) * NH + h];
            Bs[r*60 + 58] = 0.f; Bs[r*60 + 59] = 0.f;
        }
    }
    __syncthreads();

    const int tx = tid & 15, ty = tid >> 4;
    float acc[4][4] = {};
    for (int k4 = 0; k4 < 60; k4 += 4) {
        float4 a[4], b[4];
#pragma unroll
        for (int r = 0; r < 4; ++r) a[r] = *(const float4*)&As[(ty*4 + r)*60 + k4];
#pragma unroll
        for (int c = 0; c < 4; ++c) b[c] = *(const float4*)&Bs[(tx*4 + c)*60 + k4];
#pragma unroll
        for (int r = 0; r < 4; ++r)
#pragma unroll
            for (int c = 0; c < 4; ++c) {
                acc[r][c] = fmaf(a[r].x, b[c].x, acc[r][c]);
                acc[r][c] = fmaf(a[r].y, b[c].y, acc[r][c]);
                acc[r][c] = fmaf(a[r].z, b[c].z, acc[r][c]);
                acc[r][c] = fmaf(a[r].w, b[c].w, acc[r][c]);
            }
    }
#pragma unroll
    for (int r = 0; r < 4; ++r) {
        float4 o = make_float4(acc[r][0], acc[r][1], acc[r][2], acc[r][3]);
        *(float4*)&lgN[((size_t)(i0 + ty*4 + r) * NH + h) * LL + j0 + tx*4] = o;
    }
}

// ---------------- K4a: pair term + softmax + p2n, z resident in LDS ----------------
// block per i, 512 threads.
__global__ void __launch_bounds__(512) k4a_fused(
    const float* __restrict__ z, const float* __restrict__ Wpb,
    float* __restrict__ lgA,      // in: node+spatial logits; out: alpha
    float* __restrict__ feat) {
    const int i = blockIdx.x, tid = threadIdx.x;
    __shared__ float z_s[384 * 65];   // 97.5 KB, stride 65 = conflict-free
    __shared__ float a_s[NH * 384];   // 18 KB logits -> alpha
    __shared__ float red[8 * 768];    // 24 KB p2n partials

    // Phase A: stage z[i] once
    const float4* zsrc = (const float4*)(z + (size_t)i * (LL * CC));
#pragma unroll
    for (int k = 0; k < 12; ++k) {
        int idx = tid + k * 512;
        float4 v = zsrc[idx];
        int j = idx >> 4, c4 = idx & 15;
        float* d = &z_s[j * 65 + c4 * 4];
        d[0] = v.x; d[1] = v.y; d[2] = v.z; d[3] = v.w;
    }
    __syncthreads();

    // Phase B: pair term + combine with node+spatial
    if (tid < 384) {
        const int j = tid;
        float pacc[12] = {};
        const float* zrow = &z_s[j * 65];
        for (int c = 0; c < CC; ++c) {
            float zc = zrow[c];
#pragma unroll
            for (int hh = 0; hh < 12; ++hh)
                pacc[hh] = fmaf(zc, Wpb[c * NH + hh], pacc[hh]);  // uniform -> s_load
        }
        const float s3 = 0.5773502691896258f;
#pragma unroll
        for (int hh = 0; hh < 12; ++hh)
            a_s[hh * 384 + j] = lgA[((size_t)i * NH + hh) * LL + j] + pacc[hh] * s3;
    }
    __syncthreads();

    // Phase C: softmax (waves 0-5, 2 heads each), write alpha to LDS + global
    const int wv = tid >> 6, lane = tid & 63;
    if (wv < 6) {
#pragma unroll
        for (int rr = 0; rr < 2; ++rr) {
            const int h = wv * 2 + rr;
            float v[6];
#pragma unroll
            for (int k = 0; k < 6; ++k) v[k] = a_s[h * 384 + lane + k * 64];
            float m = v[0];
#pragma unroll
            for (int k = 1; k < 6; ++k) m = fmaxf(m, v[k]);
#pragma unroll
            for (int off = 32; off; off >>= 1) m = fmaxf(m, __shfl_xor(m, off));
            float s = 0.f;
#pragma unroll
            for (int k = 0; k < 6; ++k) { v[k] = expf(v[k] - m); s += v[k]; }
#pragma unroll
            for (int off = 32; off; off >>= 1) s += __shfl_xor(s, off);
            float inv = 1.f / s;
#pragma unroll
            for (int k = 0; k < 6; ++k) {
                float a = v[k] * inv;
                a_s[h * 384 + lane + k * 64] = a;
                lgA[((size_t)i * NH + h) * LL + lane + k * 64] = a;
            }
        }
    }
    __syncthreads();

    // Phase D: p2n — acc[h][c4] over this thread's 12 j values
    const int c4 = tid & 15, jc = tid >> 4;   // jc 0..31
    float4 acc[12] = {};
    const int jbase = jc * 12;
#pragma unroll
    for (int j4 = 0; j4 < 3; ++j4) {
        const int j = jbase + j4 * 4;
        float zv[4][4];
#pragma unroll
        for (int jj = 0; jj < 4; ++jj) {
            const float* zp = &z_s[(j + jj) * 65 + c4 * 4];
            zv[jj][0]=zp[0]; zv[jj][1]=zp[1]; zv[jj][2]=zp[2]; zv[jj][3]=zp[3];
        }
#pragma unroll
        for (int hh = 0; hh < 12; ++hh) {
            float4 a4 = *(const float4*)&a_s[hh * 384 + j];
            acc[hh].x = fmaf(a4.x, zv[0][0], acc[hh].x); acc[hh].y = fmaf(a4.x, zv[0][1], acc[hh].y);
            acc[hh].z = fmaf(a4.x, zv[0][2], acc[hh].z); acc[hh].w = fmaf(a4.x, zv[0][3], acc[hh].w);
            acc[hh].x = fmaf(a4.y, zv[1][0], acc[hh].x); acc[hh].y = fmaf(a4.y, zv[1][1], acc[hh].y);
            acc[hh].z = fmaf(a4.y, zv[1][2], acc[hh].z); acc[hh].w = fmaf(a4.y, zv[1][3], acc[hh].w);
            acc[hh].x = fmaf(a4.z, zv[2][0], acc[hh].x); acc[hh].y = fmaf(a4.z, zv[2][1], acc[hh].y);
            acc[hh].z = fmaf(a4.z, zv[2][2], acc[hh].z); acc[hh].w = fmaf(a4.z, zv[2][3], acc[hh].w);
            acc[hh].x = fmaf(a4.w, zv[3][0], acc[hh].x); acc[hh].y = fmaf(a4.w, zv[3][1], acc[hh].y);
            acc[hh].z = fmaf(a4.w, zv[3][2], acc[hh].z); acc[hh].w = fmaf(a4.w, zv[3][3], acc[hh].w);
        }
    }
    // reduce 4 jc groups within wave (lanes 16/32 apart)
#pragma unroll
    for (int hh = 0; hh < 12; ++hh) {
        acc[hh].x += __shfl_xor(acc[hh].x, 16); acc[hh].y += __shfl_xor(acc[hh].y, 16);
        acc[hh].z += __shfl_xor(acc[hh].z, 16); acc[hh].w += __shfl_xor(acc[hh].w, 16);
        acc[hh].x += __shfl_xor(acc[hh].x, 32); acc[hh].y += __shfl_xor(acc[hh].y, 32);
        acc[hh].z += __shfl_xor(acc[hh].z, 32); acc[hh].w += __shfl_xor(acc[hh].w, 32);
    }
    if (lane < 16) {
#pragma unroll
        for (int hh = 0; hh < 12; ++hh)
            *(float4*)&red[wv * 768 + hh * 64 + lane * 4] = acc[hh];
    }
    __syncthreads();
    if (tid < 192) {
        int hh = tid >> 4, cc = tid & 15;
        float4 s = make_float4(0.f, 0.f, 0.f, 0.f);
#pragma unroll
        for (int w = 0; w < 8; ++w) {
            float4 p = *(const float4*)&red[w * 768 + hh * 64 + cc * 4];
            s.x += p.x; s.y += p.y; s.z += p.z; s.w += p.w;
        }
        *(float4*)&feat[(size_t)i * DOUT + hh * 64 + cc * 4] = s;
    }
}

// ---------------- K4b: node + vp aggregation as GEMM ----------------
// grid (12 i-tiles, 12 h), 256 thr; wave w owns 8 i-rows; lane n < 56 cols (32 vb + 24 vp).
__global__ void __launch_bounds__(256) k4b_aggr(
    const float* __restrict__ alpha, const float* __restrict__ vb,
    const float* __restrict__ vp, float* __restrict__ feat, float* __restrict__ aggr) {
    const int it = blockIdx.x, h = blockIdx.y;
    const int tid = threadIdx.x;
    __shared__ float bs[128 * 57];
    const int i0 = it * 32;
    const int wv = __builtin_amdgcn_readfirstlane(tid >> 6);
    const int n = tid & 63;
    const float* arow0 = alpha + ((size_t)(i0 + wv * 8) * NH + h) * LL;  // uniform

    float acc[8] = {};
    for (int tile = 0; tile < 3; ++tile) {
        const int j0 = tile * 128;
        __syncthreads();
        for (int idx = tid; idx < 1792; idx += 256) {
            int jr = idx / 14, q = idx % 14;
            const float* src = (q < 8)
                ? vb + (size_t)(j0 + jr) * HV + h * 32 + q * 4
                : vp + (size_t)(j0 + jr) * HP3 + h * 24 + (q - 8) * 4;
            int c0 = (q < 8) ? q * 4 : 32 + (q - 8) * 4;
            float* d = &bs[jr * 57 + c0];
            d[0] = src[0]; d[1] = src[1]; d[2] = src[2]; d[3] = src[3];
        }
        __syncthreads();
        if (n < 56) {
            for (int j4 = 0; j4 < 32; ++j4) {
                float bv0 = bs[(j4*4+0)*57 + n];
                float bv1 = bs[(j4*4+1)*57 + n];
                float bv2 = bs[(j4*4+2)*57 + n];
                float bv3 = bs[(j4*4+3)*57 + n];
#pragma unroll
                for (int r = 0; r < 8; ++r) {
                    const float* ar = arow0 + (size_t)r * (NH * LL) + j0 + j4 * 4; // uniform -> s_load
                    acc[r] = fmaf(ar[0], bv0, acc[r]);
                    acc[r] = fmaf(ar[1], bv1, acc[r]);
                    acc[r] = fmaf(ar[2], bv2, acc[r]);
                    acc[r] = fmaf(ar[3], bv3, acc[r]);
                }
            }
        }
    }
    if (n < 56) {
#pragma unroll
        for (int r = 0; r < 8; ++r) {
            int i = i0 + wv * 8 + r;
            if (n < 32) feat[(size_t)i * DOUT + 768 + h * 32 + n] = acc[r];
            else        aggr[(size_t)i * HP3 + h * 24 + (n - 32)] = acc[r];
        }
    }
}

// ---------------- K4c: frame transform ----------------
__global__ void __launch_bounds__(128) k4c_frame(
    const float* __restrict__ aggr, const float* __restrict__ R,
    const float* __restrict__ t, float* __restrict__ feat) {
    const int i = blockIdx.x, tid = threadIdx.x;
    if (tid < NPT) {
        float d0 = aggr[(size_t)i*HP3 + tid*3 + 0] - t[i*3+0];
        float d1 = aggr[(size_t)i*HP3 + tid*3 + 1] - t[i*3+1];
        float d2 = aggr[(size_t)i*HP3 + tid*3 + 2] - t[i*3+2];
        float f0 = R[i*9+0]*d0 + R[i*9+3]*d1 + R[i*9+6]*d2;
        float f1 = R[i*9+1]*d0 + R[i*9+4]*d1 + R[i*9+7]*d2;
        float f2 = R[i*9+2]*d0 + R[i*9+5]*d1 + R[i*9+8]*d2;
        float dist = sqrtf(f0*f0 + f1*f1 + f2*f2);
        float inv = 1.f / (dist + 1e-4f);
        float* fr = feat + (size_t)i * DOUT;
        fr[1152 + tid*3+0] = f0; fr[1152 + tid*3+1] = f1; fr[1152 + tid*3+2] = f2;
        fr[1440 + tid] = dist;
        fr[1536 + tid*3+0] = f0*inv; fr[1536 + tid*3+1] = f1*inv; fr[1536 + tid*3+2] = f2*inv;
    }
}

// ---------------- K6: out proj + residual + LN1 (2 rows/block) ----------------
__global__ void __launch_bounds__(256) k6_outln(
    const float* __restrict__ feat, const float* __restrict__ Wout,
    const float* __restrict__ bout, const float* __restrict__ x,
    const float* __restrict__ g, const float* __restrict__ b, float* __restrict__ x1) {
    const int i0 = blockIdx.x * 2, tid = threadIdx.x;
    const int f = tid & 127;
    const int dg = __builtin_amdgcn_readfirstlane(tid >> 7);
    __shared__ float part[2][2][128];
    __shared__ float wsum[4];
    const float* fa0 = feat + (size_t)i0 * DOUT;
    const float* fa1 = fa0 + DOUT;
    const int dbeg = dg * 912;
    float a0[4] = {0,0,0,0}, a1[4] = {0,0,0,0};
    for (int k = 0; k < 228; ++k) {
        int d = dbeg + k * 4;
#pragma unroll
        for (int e = 0; e < 4; ++e) {
            float w = Wout[(size_t)(d + e) * FF + f];
            a0[e] = fmaf(fa0[d + e], w, a0[e]);
            a1[e] = fmaf(fa1[d + e], w, a1[e]);
        }
    }
    part[dg][0][f] = a0[0] + a0[1] + a0[2] + a0[3];
    part[dg][1][f] = a1[0] + a1[1] + a1[2] + a1[3];
    __syncthreads();

    const int ii = tid >> 7, ff = tid & 127;
    float s = part[0][ii][ff] + part[1][ii][ff] + bout[ff] + x[(size_t)(i0 + ii) * FF + ff];
    float r = s;
#pragma unroll
    for (int off = 32; off; off >>= 1) r += __shfl_xor(r, off);
    if ((tid & 63) == 0) wsum[tid >> 6] = r;
    __syncthreads();
    float mu = (wsum[ii*2] + wsum[ii*2+1]) * (1.f / FF);
    float dv = s - mu;
    r = dv * dv;
#pragma unroll
    for (int off = 32; off; off >>= 1) r += __shfl_xor(r, off);
    __syncthreads();
    if ((tid & 63) == 0) wsum[tid >> 6] = r;
    __syncthreads();
    float var = (wsum[ii*2] + wsum[ii*2+1]) * (1.f / FF);
    x1[(size_t)(i0 + ii) * FF + ff] = dv * rsqrtf(var + 1e-5f) * g[ff] + b[ff];
}

// ---------------- K7: MLP + residual + LN2 ----------------
__global__ void __launch_bounds__(128) k7_mlp(
    const float* __restrict__ x1, const float* __restrict__ W1, const float* __restrict__ b1,
    const float* __restrict__ W2, const float* __restrict__ b2,
    const float* __restrict__ W3, const float* __restrict__ b3,
    const float* __restrict__ g, const float* __restrict__ bb, float* __restrict__ out) {
    const int i = blockIdx.x, f = threadIdx.x;
    __shared__ float hbuf[FF];
    __shared__ float wsum[2];
    const float* x1row = x1 + (size_t)i * FF;
    float xv = x1row[f];
    float acc[4] = {0,0,0,0};
    for (int k = 0; k < 32; ++k) {
#pragma unroll
        for (int e = 0; e < 4; ++e) {
            int d = k * 4 + e;
            acc[e] = fmaf(x1row[d], W1[(size_t)d * FF + f], acc[e]);
        }
    }
    float h1 = fmaxf(acc[0]+acc[1]+acc[2]+acc[3] + b1[f], 0.f);
    hbuf[f] = h1; __syncthreads();
    float bcc[4] = {0,0,0,0};
    for (int k = 0; k < 32; ++k) {
#pragma unroll
        for (int e = 0; e < 4; ++e) {
            int d = k * 4 + e;
            bcc[e] = fmaf(hbuf[d], W2[(size_t)d * FF + f], bcc[e]);
        }
    }
    float h2 = fmaxf(bcc[0]+bcc[1]+bcc[2]+bcc[3] + b2[f], 0.f);
    __syncthreads(); hbuf[f] = h2; __syncthreads();
    float ccc[4] = {0,0,0,0};
    for (int k = 0; k < 32; ++k) {
#pragma unroll
        for (int e = 0; e < 4; ++e) {
            int d = k * 4 + e;
            ccc[e] = fmaf(hbuf[d], W3[(size_t)d * FF + f], ccc[e]);
        }
    }
    float s = xv + ccc[0]+ccc[1]+ccc[2]+ccc[3] + b3[f];
    float r = s;
#pragma unroll
    for (int off = 32; off; off >>= 1) r += __shfl_xor(r, off);
    if ((f & 63) == 0) wsum[f >> 6] = r;
    __syncthreads();
    float mu = (wsum[0] + wsum[1]) * (1.f / FF);
    float dv = s - mu;
    r = dv * dv;
#pragma unroll
    for (int off = 32; off; off >>= 1) r += __shfl_xor(r, off);
    __syncthreads();
    if ((f & 63) == 0) wsum[f >> 6] = r;
    __syncthreads();
    float var = (wsum[0] + wsum[1]) * (1.f / FF);
    out[(size_t)i * FF + f] = dv * rsqrtf(var + 1e-5f) * g[f] + bb[f];
}

extern "C" void kernel_launch(void* const* d_in, const int* in_sizes, int n_in,
                              void* d_out, int out_size, void* d_ws, size_t ws_size,
                              hipStream_t stream) {
    const float* R    = (const float*)d_in[0];
    const float* t    = (const float*)d_in[1];
    const float* x    = (const float*)d_in[2];
    const float* z    = (const float*)d_in[3];
    const float* Wq   = (const float*)d_in[5];
    const float* Wk   = (const float*)d_in[6];
    const float* Wv   = (const float*)d_in[7];
    const float* Wpb  = (const float*)d_in[8];
    const float* spc  = (const float*)d_in[9];
    const float* Wqp  = (const float*)d_in[10];
    const float* Wkp  = (const float*)d_in[11];
    const float* Wvp  = (const float*)d_in[12];
    const float* Wout = (const float*)d_in[13];
    const float* bout = (const float*)d_in[14];
    const float* ln1g = (const float*)d_in[15];
    const float* ln1b = (const float*)d_in[16];
    const float* W1   = (const float*)d_in[17];
    const float* b1   = (const float*)d_in[18];
    const float* W2   = (const float*)d_in[19];
    const float* b2   = (const float*)d_in[20];
    const float* W3   = (const float*)d_in[21];
    const float* b3   = (const float*)d_in[22];
    const float* ln2g = (const float*)d_in[23];
    const float* ln2b = (const float*)d_in[24];
    float* out = (float*)d_out;

    float* ws = (float*)d_ws;
    float* qb   = ws;                          // [384][384]
    float* kb   = qb   + (size_t)LL * HQK;     // [384][384]
    float* vb   = kb   + (size_t)LL * HQK;     // [384][384]
    float* qp   = vb   + (size_t)LL * HV;      // [384][288] -> global frame in place
    float* kp   = qp   + (size_t)LL * HP3;     // [384][288] -> global frame in place
    float* vp   = kp   + (size_t)LL * HP3;     // [384][288] -> global frame in place
    float* qnb  = vp   + (size_t)LL * HP3;     // [384][12]
    float* knb  = qnb  + (size_t)LL * NH;      // [384][12]
    float* gam  = knb  + (size_t)LL * NH;      // 16
    float* lgA  = gam  + 16;                   // [384][12][384]: logits, then alpha (in place)
    float* feat = lgA  + (size_t)LL * NH * LL; // [384][1824]
    float* aggr = feat + (size_t)LL * DOUT;    // [384][288]
    float* x1   = aggr + (size_t)LL * HP3;     // [384][128]

    k1a_gemm<<<dim3(63, 6), 256, 0, stream>>>(x, Wq, Wk, Wv, Wqp, Wkp, Wvp,
                                              qb, kb, vb, qp, kp, vp);
    k1b_derived<<<LL, 128, 0, stream>>>(R, t, qp, kp, vp, qnb, knb, spc, gam);
    k3_node<<<dim3(6, 6, 12), 256, 0, stream>>>(qb, kb, qp, kp, qnb, knb, gam, lgA);
    k4a_fused<<<LL, 512, 0, stream>>>(z, Wpb, lgA, feat);
    k4b_aggr<<<dim3(12, 12), 256, 0, stream>>>(lgA, vb, vp, feat, aggr);
    k4c_frame<<<LL, 128, 0, stream>>>(aggr, R, t, feat);
    k6_outln<<<LL / 2, 256, 0, stream>>>(feat, Wout, bout, x, ln1g, ln1b, x1);
    k7_mlp<<<LL, 128, 0, stream>>>(x1, W1, b1, W2, b2, W3, b3, ln2g, ln2b, out);
}

// Round 5
// 127.496 us; speedup vs baseline: 1.0634x; 1.0634x over previous
//
#include <hip/hip_runtime.h>
#include <math.h>

constexpr int LL   = 384;
constexpr int FF   = 128;
constexpr int NH   = 12;
constexpr int HQK  = 384;
constexpr int HV   = 384;
constexpr int HP3  = 288;
constexpr int NPT  = 96;
constexpr int CC   = 64;
constexpr int DOUT = 1824;

__device__ inline unsigned short f2bf(float f) {
    unsigned int u = __float_as_uint(f);
    unsigned int r = (u + 0x7fff + ((u >> 16) & 1)) >> 16;
    return (unsigned short)r;
}
__device__ inline float bf2f(unsigned short s) {
    return __uint_as_float(((unsigned int)s) << 16);
}

// ---------------- K1a: all six projections as one tiled GEMM ----------------
__global__ void __launch_bounds__(256) k1a_gemm(
    const float* __restrict__ x,
    const float* __restrict__ Wq, const float* __restrict__ Wk, const float* __restrict__ Wv,
    const float* __restrict__ Wqp, const float* __restrict__ Wkp, const float* __restrict__ Wvp,
    float* __restrict__ qb, float* __restrict__ kb, float* __restrict__ vb,
    float* __restrict__ qp, float* __restrict__ kp, float* __restrict__ vp) {
    const int ct = blockIdx.x;       // 0..62
    const int rt = blockIdx.y;       // 0..5
    const int tid = threadIdx.x;
    __shared__ float xs[64 * 132];

    const float* W; float* O; int ld, cb;
    if (ct < 12)      { W = Wq;  O = qb; ld = 384; cb = ct * 32; }
    else if (ct < 24) { W = Wk;  O = kb; ld = 384; cb = (ct - 12) * 32; }
    else if (ct < 36) { W = Wv;  O = vb; ld = 384; cb = (ct - 24) * 32; }
    else if (ct < 45) { W = Wqp; O = qp; ld = 288; cb = (ct - 36) * 32; }
    else if (ct < 54) { W = Wkp; O = kp; ld = 288; cb = (ct - 45) * 32; }
    else              { W = Wvp; O = vp; ld = 288; cb = (ct - 54) * 32; }
    const int r0 = rt * 64;

    const float4* xsrc = (const float4*)(x + (size_t)r0 * FF);
#pragma unroll
    for (int k = 0; k < 8; ++k) {
        int idx = tid + k * 256;
        float4 v = xsrc[idx];
        int row = idx >> 5, c4 = (idx & 31) * 4;
        float* d = &xs[row * 132 + c4];
        d[0] = v.x; d[1] = v.y; d[2] = v.z; d[3] = v.w;
    }
    __syncthreads();

    const int cq = (tid & 7) * 4;
    const int rr = (tid >> 3) * 2;
    const float* Wp = W + cb + cq;
    const float* xr0 = &xs[rr * 132];
    const float* xr1 = &xs[(rr + 1) * 132];
    float a00=0,a01=0,a02=0,a03=0, a10=0,a11=0,a12=0,a13=0;
#pragma unroll 8
    for (int f = 0; f < FF; ++f) {
        const float4 w = *(const float4*)(Wp + (size_t)f * ld);
        float xa = xr0[f], xb = xr1[f];
        a00 = fmaf(xa, w.x, a00); a01 = fmaf(xa, w.y, a01);
        a02 = fmaf(xa, w.z, a02); a03 = fmaf(xa, w.w, a03);
        a10 = fmaf(xb, w.x, a10); a11 = fmaf(xb, w.y, a11);
        a12 = fmaf(xb, w.z, a12); a13 = fmaf(xb, w.w, a13);
    }
    float* o0 = O + (size_t)(r0 + rr) * ld + cb + cq;
    float* o1 = o0 + ld;
    o0[0]=a00; o0[1]=a01; o0[2]=a02; o0[3]=a03;
    o1[0]=a10; o1[1]=a11; o1[2]=a12; o1[3]=a13;
}

// ---------------- K1b: rigid transforms in place + norms ----------------
__global__ void __launch_bounds__(128) k1b_derived(
    const float* __restrict__ R, const float* __restrict__ t,
    float* __restrict__ qp, float* __restrict__ kp, float* __restrict__ vp,
    float* __restrict__ qnb, float* __restrict__ knb) {
    const int i = blockIdx.x, tid = threadIdx.x;
    __shared__ float nq[NPT], nk[NPT];
    const float r00=R[i*9+0], r01=R[i*9+1], r02=R[i*9+2];
    const float r10=R[i*9+3], r11=R[i*9+4], r12=R[i*9+5];
    const float r20=R[i*9+6], r21=R[i*9+7], r22=R[i*9+8];
    const float t0=t[i*3+0], t1=t[i*3+1], t2=t[i*3+2];

    if (tid < NPT) {
        size_t base = (size_t)i * HP3 + tid * 3;
        {
            float l0=qp[base], l1=qp[base+1], l2=qp[base+2];
            float g0=r00*l0+r01*l1+r02*l2+t0;
            float g1=r10*l0+r11*l1+r12*l2+t1;
            float g2=r20*l0+r21*l1+r22*l2+t2;
            qp[base]=g0; qp[base+1]=g1; qp[base+2]=g2;
            nq[tid]=g0*g0+g1*g1+g2*g2;
        }
        {
            float l0=kp[base], l1=kp[base+1], l2=kp[base+2];
            float g0=r00*l0+r01*l1+r02*l2+t0;
            float g1=r10*l0+r11*l1+r12*l2+t1;
            float g2=r20*l0+r21*l1+r22*l2+t2;
            kp[base]=g0; kp[base+1]=g1; kp[base+2]=g2;
            nk[tid]=g0*g0+g1*g1+g2*g2;
        }
        {
            float l0=vp[base], l1=vp[base+1], l2=vp[base+2];
            float g0=r00*l0+r01*l1+r02*l2+t0;
            float g1=r10*l0+r11*l1+r12*l2+t1;
            float g2=r20*l0+r21*l1+r22*l2+t2;
            vp[base]=g0; vp[base+1]=g1; vp[base+2]=g2;
        }
    }
    __syncthreads();
    if (tid < NH) {
        float sq=0.f, sk=0.f;
#pragma unroll
        for (int p=0;p<8;++p){ sq+=nq[tid*8+p]; sk+=nk[tid*8+p]; }
        qnb[(size_t)i*NH+tid]=sq;
        knb[(size_t)i*NH+tid]=sk;
    }
}

// ---------------- K3: node+spatial logits as rank-58 bilinear GEMM ----------------
__global__ void __launch_bounds__(256) k3_node(
    const float* __restrict__ qb, const float* __restrict__ kb,
    const float* __restrict__ qp, const float* __restrict__ kp,
    const float* __restrict__ qnb, const float* __restrict__ knb,
    const float* __restrict__ spc, float* __restrict__ lgN) {
    const int it = blockIdx.x, jt = blockIdx.y, h = blockIdx.z;
    const int tid = threadIdx.x;
    __shared__ float As[64 * 60];
    __shared__ float Bs[64 * 60];
    const float g = log1pf(expf(spc[h]));
    const float s3 = 0.5773502691896258f;
    const float c1 = s3 * 0.17677669529663687f;
    const float c2 = s3 * g * (1.f / 6.f);
    const float c3 = -s3 * g * (1.f / 12.f);
    const int i0 = it * 64, j0 = jt * 64;

    for (int idx = tid; idx < 2048; idx += 256) {
        int r = idx >> 5, c = idx & 31;
        As[r*60 + c] = qb[(size_t)(i0 + r) * HQK + h*32 + c];
        Bs[r*60 + c] = kb[(size_t)(j0 + r) * HQK + h*32 + c] * c1;
    }
    for (int idx = tid; idx < 2048; idx += 256) {
        int r = idx >> 5, c = idx & 31;
        if (c < 24) {
            As[r*60 + 32 + c] = qp[(size_t)(i0+r) * HP3 + h*24 + c];
            Bs[r*60 + 32 + c] = kp[(size_t)(j0+r) * HP3 + h*24 + c] * c2;
        } else if (c == 24) {
            As[r*60 + 56] = qnb[(size_t)(i0+r) * NH + h];
            As[r*60 + 57] = 1.f;
            As[r*60 + 58] = 0.f; As[r*60 + 59] = 0.f;
            Bs[r*60 + 56] = c3;
            Bs[r*60 + 57] = c3 * knb[(size_t)(j0+r) * NH + h];
            Bs[r*60 + 58] = 0.f; Bs[r*60 + 59] = 0.f;
        }
    }
    __syncthreads();

    const int tx = tid & 15, ty = tid >> 4;
    float acc[4][4] = {};
    for (int k4 = 0; k4 < 60; k4 += 4) {
        float4 a[4], b[4];
#pragma unroll
        for (int r = 0; r < 4; ++r) a[r] = *(const float4*)&As[(ty*4 + r)*60 + k4];
#pragma unroll
        for (int c = 0; c < 4; ++c) b[c] = *(const float4*)&Bs[(tx*4 + c)*60 + k4];
#pragma unroll
        for (int r = 0; r < 4; ++r)
#pragma unroll
            for (int c = 0; c < 4; ++c) {
                acc[r][c] = fmaf(a[r].x, b[c].x, acc[r][c]);
                acc[r][c] = fmaf(a[r].y, b[c].y, acc[r][c]);
                acc[r][c] = fmaf(a[r].z, b[c].z, acc[r][c]);
                acc[r][c] = fmaf(a[r].w, b[c].w, acc[r][c]);
            }
    }
#pragma unroll
    for (int r = 0; r < 4; ++r) {
        float4 o = make_float4(acc[r][0], acc[r][1], acc[r][2], acc[r][3]);
        *(float4*)&lgN[((size_t)(i0 + ty*4 + r) * NH + h) * LL + j0 + tx*4] = o;
    }
}

// ---------------- K4a: pair term + softmax + p2n; z bf16 in LDS, red aliased ----------------
__global__ void __launch_bounds__(512, 4) k4a_fused(
    const float* __restrict__ z, const float* __restrict__ Wpb,
    float* __restrict__ lgA, float* __restrict__ feat) {
    const int i = blockIdx.x, tid = threadIdx.x;
    __shared__ __align__(16) unsigned char zu[384 * 68 * 2];  // 52.2 KB: z_s (bf16), later red
    unsigned short* z_s = (unsigned short*)zu;
    float* red = (float*)zu;                                   // aliased after barrier
    __shared__ float a_s[NH * 384];                            // 18 KB

    // Phase A: stage z[i] once as bf16
    const float4* zsrc = (const float4*)(z + (size_t)i * (LL * CC));
#pragma unroll
    for (int k = 0; k < 12; ++k) {
        int idx = tid + k * 512;
        float4 v = zsrc[idx];
        int j = idx >> 4, c4 = idx & 15;
        ushort4 pk;
        pk.x = f2bf(v.x); pk.y = f2bf(v.y); pk.z = f2bf(v.z); pk.w = f2bf(v.w);
        *(ushort4*)&z_s[j * 68 + c4 * 4] = pk;
    }
    __syncthreads();

    // Phase B: pair term + combine with node+spatial logits
    if (tid < 384) {
        const int j = tid;
        float pacc[12] = {};
        const unsigned short* zrow = &z_s[j * 68];
        for (int c = 0; c < CC; ++c) {
            float zc = bf2f(zrow[c]);
#pragma unroll
            for (int hh = 0; hh < 12; ++hh)
                pacc[hh] = fmaf(zc, Wpb[c * NH + hh], pacc[hh]);
        }
        const float s3 = 0.5773502691896258f;
#pragma unroll
        for (int hh = 0; hh < 12; ++hh)
            a_s[hh * 384 + j] = lgA[((size_t)i * NH + hh) * LL + j] + pacc[hh] * s3;
    }
    __syncthreads();

    // Phase C: softmax (waves 0-5, 2 heads each)
    const int wv = tid >> 6, lane = tid & 63;
    if (wv < 6) {
#pragma unroll
        for (int rr = 0; rr < 2; ++rr) {
            const int h = wv * 2 + rr;
            float v[6];
#pragma unroll
            for (int k = 0; k < 6; ++k) v[k] = a_s[h * 384 + lane + k * 64];
            float m = v[0];
#pragma unroll
            for (int k = 1; k < 6; ++k) m = fmaxf(m, v[k]);
#pragma unroll
            for (int off = 32; off; off >>= 1) m = fmaxf(m, __shfl_xor(m, off));
            float s = 0.f;
#pragma unroll
            for (int k = 0; k < 6; ++k) { v[k] = expf(v[k] - m); s += v[k]; }
#pragma unroll
            for (int off = 32; off; off >>= 1) s += __shfl_xor(s, off);
            float inv = 1.f / s;
#pragma unroll
            for (int k = 0; k < 6; ++k) {
                float a = v[k] * inv;
                a_s[h * 384 + lane + k * 64] = a;
                lgA[((size_t)i * NH + h) * LL + lane + k * 64] = a;
            }
        }
    }
    __syncthreads();

    // Phase D: p2n
    const int c4 = tid & 15, jc = tid >> 4;
    float4 acc[12] = {};
    const int jbase = jc * 12;
#pragma unroll
    for (int j4 = 0; j4 < 3; ++j4) {
        const int j = jbase + j4 * 4;
        float zv[4][4];
#pragma unroll
        for (int jj = 0; jj < 4; ++jj) {
            ushort4 zz = *(const ushort4*)&z_s[(j + jj) * 68 + c4 * 4];
            zv[jj][0] = bf2f(zz.x); zv[jj][1] = bf2f(zz.y);
            zv[jj][2] = bf2f(zz.z); zv[jj][3] = bf2f(zz.w);
        }
#pragma unroll
        for (int hh = 0; hh < 12; ++hh) {
            float4 a4 = *(const float4*)&a_s[hh * 384 + j];
            acc[hh].x = fmaf(a4.x, zv[0][0], acc[hh].x); acc[hh].y = fmaf(a4.x, zv[0][1], acc[hh].y);
            acc[hh].z = fmaf(a4.x, zv[0][2], acc[hh].z); acc[hh].w = fmaf(a4.x, zv[0][3], acc[hh].w);
            acc[hh].x = fmaf(a4.y, zv[1][0], acc[hh].x); acc[hh].y = fmaf(a4.y, zv[1][1], acc[hh].y);
            acc[hh].z = fmaf(a4.y, zv[1][2], acc[hh].z); acc[hh].w = fmaf(a4.y, zv[1][3], acc[hh].w);
            acc[hh].x = fmaf(a4.z, zv[2][0], acc[hh].x); acc[hh].y = fmaf(a4.z, zv[2][1], acc[hh].y);
            acc[hh].z = fmaf(a4.z, zv[2][2], acc[hh].z); acc[hh].w = fmaf(a4.z, zv[2][3], acc[hh].w);
            acc[hh].x = fmaf(a4.w, zv[3][0], acc[hh].x); acc[hh].y = fmaf(a4.w, zv[3][1], acc[hh].y);
            acc[hh].z = fmaf(a4.w, zv[3][2], acc[hh].z); acc[hh].w = fmaf(a4.w, zv[3][3], acc[hh].w);
        }
    }
    // all z_s reads done before red (aliased) writes
    __syncthreads();
#pragma unroll
    for (int hh = 0; hh < 12; ++hh) {
        acc[hh].x += __shfl_xor(acc[hh].x, 16); acc[hh].y += __shfl_xor(acc[hh].y, 16);
        acc[hh].z += __shfl_xor(acc[hh].z, 16); acc[hh].w += __shfl_xor(acc[hh].w, 16);
        acc[hh].x += __shfl_xor(acc[hh].x, 32); acc[hh].y += __shfl_xor(acc[hh].y, 32);
        acc[hh].z += __shfl_xor(acc[hh].z, 32); acc[hh].w += __shfl_xor(acc[hh].w, 32);
    }
    if (lane < 16) {
#pragma unroll
        for (int hh = 0; hh < 12; ++hh)
            *(float4*)&red[wv * 768 + hh * 64 + lane * 4] = acc[hh];
    }
    __syncthreads();
    if (tid < 192) {
        int hh = tid >> 4, cc = tid & 15;
        float4 s = make_float4(0.f, 0.f, 0.f, 0.f);
#pragma unroll
        for (int w = 0; w < 8; ++w) {
            float4 p = *(const float4*)&red[w * 768 + hh * 64 + cc * 4];
            s.x += p.x; s.y += p.y; s.z += p.z; s.w += p.w;
        }
        *(float4*)&feat[(size_t)i * DOUT + hh * 64 + cc * 4] = s;
    }
}

// ---------------- K4b: node + vp aggregation. grid (24 it, 12 h), 256 thr ----------------
__global__ void __launch_bounds__(256) k4b_aggr(
    const float* __restrict__ alpha, const float* __restrict__ vb,
    const float* __restrict__ vp, float* __restrict__ feat, float* __restrict__ aggr) {
    const int it = blockIdx.x, h = blockIdx.y;
    const int tid = threadIdx.x;
    __shared__ float bs[128 * 57];
    const int i0 = it * 16;
    const int wv = __builtin_amdgcn_readfirstlane(tid >> 6);
    const int n = tid & 63;
    const float* arow0 = alpha + ((size_t)(i0 + wv * 4) * NH + h) * LL;

    float acc[4] = {};
    for (int tile = 0; tile < 3; ++tile) {
        const int j0 = tile * 128;
        __syncthreads();
        for (int idx = tid; idx < 1792; idx += 256) {
            int jr = idx / 14, q2 = idx % 14;
            const float* src = (q2 < 8)
                ? vb + (size_t)(j0 + jr) * HV + h * 32 + q2 * 4
                : vp + (size_t)(j0 + jr) * HP3 + h * 24 + (q2 - 8) * 4;
            int c0 = (q2 < 8) ? q2 * 4 : 32 + (q2 - 8) * 4;
            float* d = &bs[jr * 57 + c0];
            d[0] = src[0]; d[1] = src[1]; d[2] = src[2]; d[3] = src[3];
        }
        __syncthreads();
        if (n < 56) {
            for (int j4 = 0; j4 < 32; ++j4) {
                float bv0 = bs[(j4*4+0)*57 + n];
                float bv1 = bs[(j4*4+1)*57 + n];
                float bv2 = bs[(j4*4+2)*57 + n];
                float bv3 = bs[(j4*4+3)*57 + n];
#pragma unroll
                for (int r = 0; r < 4; ++r) {
                    const float* ar = arow0 + (size_t)r * (NH * LL) + j0 + j4 * 4;
                    acc[r] = fmaf(ar[0], bv0, acc[r]);
                    acc[r] = fmaf(ar[1], bv1, acc[r]);
                    acc[r] = fmaf(ar[2], bv2, acc[r]);
                    acc[r] = fmaf(ar[3], bv3, acc[r]);
                }
            }
        }
    }
    if (n < 56) {
#pragma unroll
        for (int r = 0; r < 4; ++r) {
            int i = i0 + wv * 4 + r;
            if (n < 32) feat[(size_t)i * DOUT + 768 + h * 32 + n] = acc[r];
            else        aggr[(size_t)i * HP3 + h * 24 + (n - 32)] = acc[r];
        }
    }
}

// ---------------- K5: fused epilogue: frame transform + out-proj + LN1 + MLP + LN2 ----------------
// grid 192 (2 rows/block), 512 thr.
__global__ void __launch_bounds__(512) k5_epi(
    const float* __restrict__ aggr, const float* __restrict__ R, const float* __restrict__ t,
    float* __restrict__ feat, const float* __restrict__ Wout, const float* __restrict__ bout,
    const float* __restrict__ x, const float* __restrict__ ln1g, const float* __restrict__ ln1b,
    const float* __restrict__ W1, const float* __restrict__ b1,
    const float* __restrict__ W2, const float* __restrict__ b2,
    const float* __restrict__ W3, const float* __restrict__ b3,
    const float* __restrict__ ln2g, const float* __restrict__ ln2b,
    float* __restrict__ out) {
    const int i0 = blockIdx.x * 2, tid = threadIdx.x;
    __shared__ float part[4][2][128];
    __shared__ float x1s[2][128];
    __shared__ float hbA[2][128], hbB[2][128];
    __shared__ float wsA[4], wsB[4];

    // Phase 0: spatial features (frame transform) for the two rows
    {
        const int ii = tid >> 8, pt = tid & 255;
        if (pt < NPT) {
            const int i = i0 + ii;
            float d0 = aggr[(size_t)i*HP3 + pt*3 + 0] - t[i*3+0];
            float d1 = aggr[(size_t)i*HP3 + pt*3 + 1] - t[i*3+1];
            float d2 = aggr[(size_t)i*HP3 + pt*3 + 2] - t[i*3+2];
            float f0 = R[i*9+0]*d0 + R[i*9+3]*d1 + R[i*9+6]*d2;
            float f1 = R[i*9+1]*d0 + R[i*9+4]*d1 + R[i*9+7]*d2;
            float f2 = R[i*9+2]*d0 + R[i*9+5]*d1 + R[i*9+8]*d2;
            float dist = sqrtf(f0*f0 + f1*f1 + f2*f2);
            float inv = 1.f / (dist + 1e-4f);
            float* fr = feat + (size_t)i * DOUT;
            fr[1152 + pt*3+0] = f0; fr[1152 + pt*3+1] = f1; fr[1152 + pt*3+2] = f2;
            fr[1440 + pt] = dist;
            fr[1536 + pt*3+0] = f0*inv; fr[1536 + pt*3+1] = f1*inv; fr[1536 + pt*3+2] = f2*inv;
        }
    }
    __syncthreads();

    // Phase 1: out projection, split-K=4
    {
        const int f = tid & 127, q = tid >> 7;
        const float* fa0 = feat + (size_t)i0 * DOUT;
        const float* fa1 = fa0 + DOUT;
        const int dbeg = q * 456;
        float a0[4] = {0,0,0,0}, a1[4] = {0,0,0,0};
        for (int k = 0; k < 114; ++k) {
            int d = dbeg + k * 4;
#pragma unroll
            for (int e = 0; e < 4; ++e) {
                float w = Wout[(size_t)(d + e) * FF + f];
                a0[e] = fmaf(fa0[d + e], w, a0[e]);
                a1[e] = fmaf(fa1[d + e], w, a1[e]);
            }
        }
        part[q][0][f] = a0[0] + a0[1] + a0[2] + a0[3];
        part[q][1][f] = a1[0] + a1[1] + a1[2] + a1[3];
    }
    __syncthreads();

    // LN1 -> x1s
    float s1 = 0.f, dv1 = 0.f;
    {
        if (tid < 256) {
            const int ii = tid >> 7, ff = tid & 127;
            s1 = part[0][ii][ff] + part[1][ii][ff] + part[2][ii][ff] + part[3][ii][ff]
               + bout[ff] + x[(size_t)(i0 + ii) * FF + ff];
            float r = s1;
#pragma unroll
            for (int off = 32; off; off >>= 1) r += __shfl_xor(r, off);
            if ((tid & 63) == 0) wsA[tid >> 6] = r;
        }
        __syncthreads();
        if (tid < 256) {
            const int ii = tid >> 7;
            float mu = (wsA[ii*2] + wsA[ii*2+1]) * (1.f / FF);
            dv1 = s1 - mu;
            float r = dv1 * dv1;
#pragma unroll
            for (int off = 32; off; off >>= 1) r += __shfl_xor(r, off);
            if ((tid & 63) == 0) wsB[tid >> 6] = r;
        }
        __syncthreads();
        if (tid < 256) {
            const int ii = tid >> 7, ff = tid & 127;
            float var = (wsB[ii*2] + wsB[ii*2+1]) * (1.f / FF);
            x1s[ii][ff] = dv1 * rsqrtf(var + 1e-5f) * ln1g[ff] + ln1b[ff];
        }
        __syncthreads();
    }

    // Phase 2: MLP, split-K=2 per layer
    const int g = tid >> 8, mi = (tid >> 7) & 1, mf = tid & 127;
    // L1
    {
        const float* src = x1s[mi];
        float p0=0,p1=0,p2=0,p3=0;
        const int d0 = g * 64;
        for (int k = 0; k < 16; ++k) {
            int d = d0 + k * 4;
            p0 = fmaf(src[d+0], W1[(size_t)(d+0)*FF + mf], p0);
            p1 = fmaf(src[d+1], W1[(size_t)(d+1)*FF + mf], p1);
            p2 = fmaf(src[d+2], W1[(size_t)(d+2)*FF + mf], p2);
            p3 = fmaf(src[d+3], W1[(size_t)(d+3)*FF + mf], p3);
        }
        part[g][mi][mf] = p0 + p1 + p2 + p3;
    }
    __syncthreads();
    if (tid < 256) hbA[mi][mf] = fmaxf(part[0][mi][mf] + part[1][mi][mf] + b1[mf], 0.f);
    __syncthreads();
    // L2
    {
        const float* src = hbA[mi];
        float p0=0,p1=0,p2=0,p3=0;
        const int d0 = g * 64;
        for (int k = 0; k < 16; ++k) {
            int d = d0 + k * 4;
            p0 = fmaf(src[d+0], W2[(size_t)(d+0)*FF + mf], p0);
            p1 = fmaf(src[d+1], W2[(size_t)(d+1)*FF + mf], p1);
            p2 = fmaf(src[d+2], W2[(size_t)(d+2)*FF + mf], p2);
            p3 = fmaf(src[d+3], W2[(size_t)(d+3)*FF + mf], p3);
        }
        part[g][mi][mf] = p0 + p1 + p2 + p3;
    }
    __syncthreads();
    if (tid < 256) hbB[mi][mf] = fmaxf(part[0][mi][mf] + part[1][mi][mf] + b2[mf], 0.f);
    __syncthreads();
    // L3
    {
        const float* src = hbB[mi];
        float p0=0,p1=0,p2=0,p3=0;
        const int d0 = g * 64;
        for (int k = 0; k < 16; ++k) {
            int d = d0 + k * 4;
            p0 = fmaf(src[d+0], W3[(size_t)(d+0)*FF + mf], p0);
            p1 = fmaf(src[d+1], W3[(size_t)(d+1)*FF + mf], p1);
            p2 = fmaf(src[d+2], W3[(size_t)(d+2)*FF + mf], p2);
            p3 = fmaf(src[d+3], W3[(size_t)(d+3)*FF + mf], p3);
        }
        part[g][mi][mf] = p0 + p1 + p2 + p3;
    }
    __syncthreads();

    // residual + LN2 -> out
    float s2 = 0.f, dv2 = 0.f;
    if (tid < 256) {
        s2 = x1s[mi][mf] + part[0][mi][mf] + part[1][mi][mf] + b3[mf];
        float r = s2;
#pragma unroll
        for (int off = 32; off; off >>= 1) r += __shfl_xor(r, off);
        if ((tid & 63) == 0) wsA[tid >> 6] = r;
    }
    __syncthreads();
    if (tid < 256) {
        float mu = (wsA[mi*2] + wsA[mi*2+1]) * (1.f / FF);
        dv2 = s2 - mu;
        float r = dv2 * dv2;
#pragma unroll
        for (int off = 32; off; off >>= 1) r += __shfl_xor(r, off);
        if ((tid & 63) == 0) wsB[tid >> 6] = r;
    }
    __syncthreads();
    if (tid < 256) {
        float var = (wsB[mi*2] + wsB[mi*2+1]) * (1.f / FF);
        out[(size_t)(i0 + mi) * FF + mf] = dv2 * rsqrtf(var + 1e-5f) * ln2g[mf] + ln2b[mf];
    }
}

extern "C" void kernel_launch(void* const* d_in, const int* in_sizes, int n_in,
                              void* d_out, int out_size, void* d_ws, size_t ws_size,
                              hipStream_t stream) {
    const float* R    = (const float*)d_in[0];
    const float* t    = (const float*)d_in[1];
    const float* x    = (const float*)d_in[2];
    const float* z    = (const float*)d_in[3];
    const float* Wq   = (const float*)d_in[5];
    const float* Wk   = (const float*)d_in[6];
    const float* Wv   = (const float*)d_in[7];
    const float* Wpb  = (const float*)d_in[8];
    const float* spc  = (const float*)d_in[9];
    const float* Wqp  = (const float*)d_in[10];
    const float* Wkp  = (const float*)d_in[11];
    const float* Wvp  = (const float*)d_in[12];
    const float* Wout = (const float*)d_in[13];
    const float* bout = (const float*)d_in[14];
    const float* ln1g = (const float*)d_in[15];
    const float* ln1b = (const float*)d_in[16];
    const float* W1   = (const float*)d_in[17];
    const float* b1   = (const float*)d_in[18];
    const float* W2   = (const float*)d_in[19];
    const float* b2   = (const float*)d_in[20];
    const float* W3   = (const float*)d_in[21];
    const float* b3   = (const float*)d_in[22];
    const float* ln2g = (const float*)d_in[23];
    const float* ln2b = (const float*)d_in[24];
    float* out = (float*)d_out;

    float* ws = (float*)d_ws;
    float* qb   = ws;
    float* kb   = qb   + (size_t)LL * HQK;
    float* vb   = kb   + (size_t)LL * HQK;
    float* qp   = vb   + (size_t)LL * HV;
    float* kp   = qp   + (size_t)LL * HP3;
    float* vp   = kp   + (size_t)LL * HP3;
    float* qnb  = vp   + (size_t)LL * HP3;
    float* knb  = qnb  + (size_t)LL * NH;
    float* lgA  = knb  + (size_t)LL * NH;       // [384][12][384] logits -> alpha
    float* feat = lgA  + (size_t)LL * NH * LL;  // [384][1824]
    float* aggr = feat + (size_t)LL * DOUT;     // [384][288]

    k1a_gemm<<<dim3(63, 6), 256, 0, stream>>>(x, Wq, Wk, Wv, Wqp, Wkp, Wvp,
                                              qb, kb, vb, qp, kp, vp);
    k1b_derived<<<LL, 128, 0, stream>>>(R, t, qp, kp, vp, qnb, knb);
    k3_node<<<dim3(6, 6, 12), 256, 0, stream>>>(qb, kb, qp, kp, qnb, knb, spc, lgA);
    k4a_fused<<<LL, 512, 0, stream>>>(z, Wpb, lgA, feat);
    k4b_aggr<<<dim3(24, 12), 256, 0, stream>>>(lgA, vb, vp, feat, aggr);
    k5_epi<<<LL / 2, 512, 0, stream>>>(aggr, R, t, feat, Wout, bout, x, ln1g, ln1b,
                                       W1, b1, W2, b2, W3, b3, ln2g, ln2b, out);
}

// Round 6
// 112.680 us; speedup vs baseline: 1.2032x; 1.1315x over previous
//
#include <hip/hip_runtime.h>
#include <math.h>

constexpr int LL   = 384;
constexpr int FF   = 128;
constexpr int NH   = 12;
constexpr int HQK  = 384;
constexpr int HV   = 384;
constexpr int HP3  = 288;
constexpr int NPT  = 96;
constexpr int CC   = 64;
constexpr int DOUT = 1824;

__device__ inline unsigned short f2bf(float f) {
    unsigned int u = __float_as_uint(f);
    unsigned int r = (u + 0x7fff + ((u >> 16) & 1)) >> 16;
    return (unsigned short)r;
}
__device__ inline float bf2f(unsigned short s) {
    return __uint_as_float(((unsigned int)s) << 16);
}

// ---------------- K1a: all six projections as one tiled GEMM ----------------
__global__ void __launch_bounds__(256) k1a_gemm(
    const float* __restrict__ x,
    const float* __restrict__ Wq, const float* __restrict__ Wk, const float* __restrict__ Wv,
    const float* __restrict__ Wqp, const float* __restrict__ Wkp, const float* __restrict__ Wvp,
    float* __restrict__ qb, float* __restrict__ kb, float* __restrict__ vb,
    float* __restrict__ qp, float* __restrict__ kp, float* __restrict__ vp) {
    const int ct = blockIdx.x;       // 0..62
    const int rt = blockIdx.y;       // 0..5
    const int tid = threadIdx.x;
    __shared__ float xs[64 * 132];

    const float* W; float* O; int ld, cb;
    if (ct < 12)      { W = Wq;  O = qb; ld = 384; cb = ct * 32; }
    else if (ct < 24) { W = Wk;  O = kb; ld = 384; cb = (ct - 12) * 32; }
    else if (ct < 36) { W = Wv;  O = vb; ld = 384; cb = (ct - 24) * 32; }
    else if (ct < 45) { W = Wqp; O = qp; ld = 288; cb = (ct - 36) * 32; }
    else if (ct < 54) { W = Wkp; O = kp; ld = 288; cb = (ct - 45) * 32; }
    else              { W = Wvp; O = vp; ld = 288; cb = (ct - 54) * 32; }
    const int r0 = rt * 64;

    const float4* xsrc = (const float4*)(x + (size_t)r0 * FF);
#pragma unroll
    for (int k = 0; k < 8; ++k) {
        int idx = tid + k * 256;
        float4 v = xsrc[idx];
        int row = idx >> 5, c4 = (idx & 31) * 4;
        float* d = &xs[row * 132 + c4];
        d[0] = v.x; d[1] = v.y; d[2] = v.z; d[3] = v.w;
    }
    __syncthreads();

    const int cq = (tid & 7) * 4;
    const int rr = (tid >> 3) * 2;
    const float* Wp = W + cb + cq;
    const float* xr0 = &xs[rr * 132];
    const float* xr1 = &xs[(rr + 1) * 132];
    float a00=0,a01=0,a02=0,a03=0, a10=0,a11=0,a12=0,a13=0;
#pragma unroll 8
    for (int f = 0; f < FF; ++f) {
        const float4 w = *(const float4*)(Wp + (size_t)f * ld);
        float xa = xr0[f], xb = xr1[f];
        a00 = fmaf(xa, w.x, a00); a01 = fmaf(xa, w.y, a01);
        a02 = fmaf(xa, w.z, a02); a03 = fmaf(xa, w.w, a03);
        a10 = fmaf(xb, w.x, a10); a11 = fmaf(xb, w.y, a11);
        a12 = fmaf(xb, w.z, a12); a13 = fmaf(xb, w.w, a13);
    }
    float* o0 = O + (size_t)(r0 + rr) * ld + cb + cq;
    float* o1 = o0 + ld;
    o0[0]=a00; o0[1]=a01; o0[2]=a02; o0[3]=a03;
    o1[0]=a10; o1[1]=a11; o1[2]=a12; o1[3]=a13;
}

// ---------------- K1b: rigid transforms in place + norms ----------------
__global__ void __launch_bounds__(128) k1b_derived(
    const float* __restrict__ R, const float* __restrict__ t,
    float* __restrict__ qp, float* __restrict__ kp, float* __restrict__ vp,
    float* __restrict__ qnb, float* __restrict__ knb) {
    const int i = blockIdx.x, tid = threadIdx.x;
    __shared__ float nq[NPT], nk[NPT];
    const float r00=R[i*9+0], r01=R[i*9+1], r02=R[i*9+2];
    const float r10=R[i*9+3], r11=R[i*9+4], r12=R[i*9+5];
    const float r20=R[i*9+6], r21=R[i*9+7], r22=R[i*9+8];
    const float t0=t[i*3+0], t1=t[i*3+1], t2=t[i*3+2];

    if (tid < NPT) {
        size_t base = (size_t)i * HP3 + tid * 3;
        {
            float l0=qp[base], l1=qp[base+1], l2=qp[base+2];
            float g0=r00*l0+r01*l1+r02*l2+t0;
            float g1=r10*l0+r11*l1+r12*l2+t1;
            float g2=r20*l0+r21*l1+r22*l2+t2;
            qp[base]=g0; qp[base+1]=g1; qp[base+2]=g2;
            nq[tid]=g0*g0+g1*g1+g2*g2;
        }
        {
            float l0=kp[base], l1=kp[base+1], l2=kp[base+2];
            float g0=r00*l0+r01*l1+r02*l2+t0;
            float g1=r10*l0+r11*l1+r12*l2+t1;
            float g2=r20*l0+r21*l1+r22*l2+t2;
            kp[base]=g0; kp[base+1]=g1; kp[base+2]=g2;
            nk[tid]=g0*g0+g1*g1+g2*g2;
        }
        {
            float l0=vp[base], l1=vp[base+1], l2=vp[base+2];
            float g0=r00*l0+r01*l1+r02*l2+t0;
            float g1=r10*l0+r11*l1+r12*l2+t1;
            float g2=r20*l0+r21*l1+r22*l2+t2;
            vp[base]=g0; vp[base+1]=g1; vp[base+2]=g2;
        }
    }
    __syncthreads();
    if (tid < NH) {
        float sq=0.f, sk=0.f;
#pragma unroll
        for (int p=0;p<8;++p){ sq+=nq[tid*8+p]; sk+=nk[tid*8+p]; }
        qnb[(size_t)i*NH+tid]=sq;
        knb[(size_t)i*NH+tid]=sk;
    }
}

// ---------------- K3: node+spatial logits as rank-58 bilinear GEMM ----------------
__global__ void __launch_bounds__(256) k3_node(
    const float* __restrict__ qb, const float* __restrict__ kb,
    const float* __restrict__ qp, const float* __restrict__ kp,
    const float* __restrict__ qnb, const float* __restrict__ knb,
    const float* __restrict__ spc, float* __restrict__ lgN) {
    const int it = blockIdx.x, jt = blockIdx.y, h = blockIdx.z;
    const int tid = threadIdx.x;
    __shared__ float As[64 * 60];
    __shared__ float Bs[64 * 60];
    const float g = log1pf(expf(spc[h]));
    const float s3 = 0.5773502691896258f;
    const float c1 = s3 * 0.17677669529663687f;
    const float c2 = s3 * g * (1.f / 6.f);
    const float c3 = -s3 * g * (1.f / 12.f);
    const int i0 = it * 64, j0 = jt * 64;

    for (int idx = tid; idx < 2048; idx += 256) {
        int r = idx >> 5, c = idx & 31;
        As[r*60 + c] = qb[(size_t)(i0 + r) * HQK + h*32 + c];
        Bs[r*60 + c] = kb[(size_t)(j0 + r) * HQK + h*32 + c] * c1;
    }
    for (int idx = tid; idx < 2048; idx += 256) {
        int r = idx >> 5, c = idx & 31;
        if (c < 24) {
            As[r*60 + 32 + c] = qp[(size_t)(i0+r) * HP3 + h*24 + c];
            Bs[r*60 + 32 + c] = kp[(size_t)(j0+r) * HP3 + h*24 + c] * c2;
        } else if (c == 24) {
            As[r*60 + 56] = qnb[(size_t)(i0+r) * NH + h];
            As[r*60 + 57] = 1.f;
            As[r*60 + 58] = 0.f; As[r*60 + 59] = 0.f;
            Bs[r*60 + 56] = c3;
            Bs[r*60 + 57] = c3 * knb[(size_t)(j0+r) * NH + h];
            Bs[r*60 + 58] = 0.f; Bs[r*60 + 59] = 0.f;
        }
    }
    __syncthreads();

    const int tx = tid & 15, ty = tid >> 4;
    float acc[4][4] = {};
    for (int k4 = 0; k4 < 60; k4 += 4) {
        float4 a[4], b[4];
#pragma unroll
        for (int r = 0; r < 4; ++r) a[r] = *(const float4*)&As[(ty*4 + r)*60 + k4];
#pragma unroll
        for (int c = 0; c < 4; ++c) b[c] = *(const float4*)&Bs[(tx*4 + c)*60 + k4];
#pragma unroll
        for (int r = 0; r < 4; ++r)
#pragma unroll
            for (int c = 0; c < 4; ++c) {
                acc[r][c] = fmaf(a[r].x, b[c].x, acc[r][c]);
                acc[r][c] = fmaf(a[r].y, b[c].y, acc[r][c]);
                acc[r][c] = fmaf(a[r].z, b[c].z, acc[r][c]);
                acc[r][c] = fmaf(a[r].w, b[c].w, acc[r][c]);
            }
    }
#pragma unroll
    for (int r = 0; r < 4; ++r) {
        float4 o = make_float4(acc[r][0], acc[r][1], acc[r][2], acc[r][3]);
        *(float4*)&lgN[((size_t)(i0 + ty*4 + r) * NH + h) * LL + j0 + tx*4] = o;
    }
}

// ---------------- K4a: pair term + softmax + p2n; z bf16 in LDS, red aliased ----------------
__global__ void __launch_bounds__(512, 4) k4a_fused(
    const float* __restrict__ z, const float* __restrict__ Wpb,
    float* __restrict__ lgA, float* __restrict__ feat) {
    const int i = blockIdx.x, tid = threadIdx.x;
    __shared__ __align__(16) unsigned char zu[384 * 68 * 2];  // 52.2 KB: z_s (bf16), later red
    unsigned short* z_s = (unsigned short*)zu;
    float* red = (float*)zu;                                   // aliased after barrier
    __shared__ float a_s[NH * 384];                            // 18 KB

    // Phase A: stage z[i] once as bf16
    const float4* zsrc = (const float4*)(z + (size_t)i * (LL * CC));
#pragma unroll
    for (int k = 0; k < 12; ++k) {
        int idx = tid + k * 512;
        float4 v = zsrc[idx];
        int j = idx >> 4, c4 = idx & 15;
        ushort4 pk;
        pk.x = f2bf(v.x); pk.y = f2bf(v.y); pk.z = f2bf(v.z); pk.w = f2bf(v.w);
        *(ushort4*)&z_s[j * 68 + c4 * 4] = pk;
    }
    __syncthreads();

    // Phase B: pair term + combine with node+spatial logits
    if (tid < 384) {
        const int j = tid;
        float pacc[12] = {};
        const unsigned short* zrow = &z_s[j * 68];
        for (int c = 0; c < CC; ++c) {
            float zc = bf2f(zrow[c]);
#pragma unroll
            for (int hh = 0; hh < 12; ++hh)
                pacc[hh] = fmaf(zc, Wpb[c * NH + hh], pacc[hh]);
        }
        const float s3 = 0.5773502691896258f;
#pragma unroll
        for (int hh = 0; hh < 12; ++hh)
            a_s[hh * 384 + j] = lgA[((size_t)i * NH + hh) * LL + j] + pacc[hh] * s3;
    }
    __syncthreads();

    // Phase C: softmax (waves 0-5, 2 heads each)
    const int wv = tid >> 6, lane = tid & 63;
    if (wv < 6) {
#pragma unroll
        for (int rr = 0; rr < 2; ++rr) {
            const int h = wv * 2 + rr;
            float v[6];
#pragma unroll
            for (int k = 0; k < 6; ++k) v[k] = a_s[h * 384 + lane + k * 64];
            float m = v[0];
#pragma unroll
            for (int k = 1; k < 6; ++k) m = fmaxf(m, v[k]);
#pragma unroll
            for (int off = 32; off; off >>= 1) m = fmaxf(m, __shfl_xor(m, off));
            float s = 0.f;
#pragma unroll
            for (int k = 0; k < 6; ++k) { v[k] = expf(v[k] - m); s += v[k]; }
#pragma unroll
            for (int off = 32; off; off >>= 1) s += __shfl_xor(s, off);
            float inv = 1.f / s;
#pragma unroll
            for (int k = 0; k < 6; ++k) {
                float a = v[k] * inv;
                a_s[h * 384 + lane + k * 64] = a;
                lgA[((size_t)i * NH + h) * LL + lane + k * 64] = a;
            }
        }
    }
    __syncthreads();

    // Phase D: p2n
    const int c4 = tid & 15, jc = tid >> 4;
    float4 acc[12] = {};
    const int jbase = jc * 12;
#pragma unroll
    for (int j4 = 0; j4 < 3; ++j4) {
        const int j = jbase + j4 * 4;
        float zv[4][4];
#pragma unroll
        for (int jj = 0; jj < 4; ++jj) {
            ushort4 zz = *(const ushort4*)&z_s[(j + jj) * 68 + c4 * 4];
            zv[jj][0] = bf2f(zz.x); zv[jj][1] = bf2f(zz.y);
            zv[jj][2] = bf2f(zz.z); zv[jj][3] = bf2f(zz.w);
        }
#pragma unroll
        for (int hh = 0; hh < 12; ++hh) {
            float4 a4 = *(const float4*)&a_s[hh * 384 + j];
            acc[hh].x = fmaf(a4.x, zv[0][0], acc[hh].x); acc[hh].y = fmaf(a4.x, zv[0][1], acc[hh].y);
            acc[hh].z = fmaf(a4.x, zv[0][2], acc[hh].z); acc[hh].w = fmaf(a4.x, zv[0][3], acc[hh].w);
            acc[hh].x = fmaf(a4.y, zv[1][0], acc[hh].x); acc[hh].y = fmaf(a4.y, zv[1][1], acc[hh].y);
            acc[hh].z = fmaf(a4.y, zv[1][2], acc[hh].z); acc[hh].w = fmaf(a4.y, zv[1][3], acc[hh].w);
            acc[hh].x = fmaf(a4.z, zv[2][0], acc[hh].x); acc[hh].y = fmaf(a4.z, zv[2][1], acc[hh].y);
            acc[hh].z = fmaf(a4.z, zv[2][2], acc[hh].z); acc[hh].w = fmaf(a4.z, zv[2][3], acc[hh].w);
            acc[hh].x = fmaf(a4.w, zv[3][0], acc[hh].x); acc[hh].y = fmaf(a4.w, zv[3][1], acc[hh].y);
            acc[hh].z = fmaf(a4.w, zv[3][2], acc[hh].z); acc[hh].w = fmaf(a4.w, zv[3][3], acc[hh].w);
        }
    }
    // all z_s reads done before red (aliased) writes
    __syncthreads();
#pragma unroll
    for (int hh = 0; hh < 12; ++hh) {
        acc[hh].x += __shfl_xor(acc[hh].x, 16); acc[hh].y += __shfl_xor(acc[hh].y, 16);
        acc[hh].z += __shfl_xor(acc[hh].z, 16); acc[hh].w += __shfl_xor(acc[hh].w, 16);
        acc[hh].x += __shfl_xor(acc[hh].x, 32); acc[hh].y += __shfl_xor(acc[hh].y, 32);
        acc[hh].z += __shfl_xor(acc[hh].z, 32); acc[hh].w += __shfl_xor(acc[hh].w, 32);
    }
    if (lane < 16) {
#pragma unroll
        for (int hh = 0; hh < 12; ++hh)
            *(float4*)&red[wv * 768 + hh * 64 + lane * 4] = acc[hh];
    }
    __syncthreads();
    if (tid < 192) {
        int hh = tid >> 4, cc = tid & 15;
        float4 s = make_float4(0.f, 0.f, 0.f, 0.f);
#pragma unroll
        for (int w = 0; w < 8; ++w) {
            float4 p = *(const float4*)&red[w * 768 + hh * 64 + cc * 4];
            s.x += p.x; s.y += p.y; s.z += p.z; s.w += p.w;
        }
        *(float4*)&feat[(size_t)i * DOUT + hh * 64 + cc * 4] = s;
    }
}

// ---------------- K4b: node + vp aggregation + frame transform. grid (24 it, 12 h) ----------------
__global__ void __launch_bounds__(256) k4b_aggr(
    const float* __restrict__ alpha, const float* __restrict__ vb,
    const float* __restrict__ vp, const float* __restrict__ R,
    const float* __restrict__ t, float* __restrict__ feat) {
    const int it = blockIdx.x, h = blockIdx.y;
    const int tid = threadIdx.x;
    __shared__ float bs[128 * 57];
    __shared__ float sa[16][24];
    const int i0 = it * 16;
    const int wv = __builtin_amdgcn_readfirstlane(tid >> 6);
    const int n = tid & 63;
    const float* arow0 = alpha + ((size_t)(i0 + wv * 4) * NH + h) * LL;

    float acc[4] = {};
    for (int tile = 0; tile < 3; ++tile) {
        const int j0 = tile * 128;
        __syncthreads();
        for (int idx = tid; idx < 1792; idx += 256) {
            int jr = idx / 14, q2 = idx % 14;
            const float* src = (q2 < 8)
                ? vb + (size_t)(j0 + jr) * HV + h * 32 + q2 * 4
                : vp + (size_t)(j0 + jr) * HP3 + h * 24 + (q2 - 8) * 4;
            int c0 = (q2 < 8) ? q2 * 4 : 32 + (q2 - 8) * 4;
            float* d = &bs[jr * 57 + c0];
            d[0] = src[0]; d[1] = src[1]; d[2] = src[2]; d[3] = src[3];
        }
        __syncthreads();
        if (n < 56) {
            for (int j4 = 0; j4 < 32; ++j4) {
                float bv0 = bs[(j4*4+0)*57 + n];
                float bv1 = bs[(j4*4+1)*57 + n];
                float bv2 = bs[(j4*4+2)*57 + n];
                float bv3 = bs[(j4*4+3)*57 + n];
#pragma unroll
                for (int r = 0; r < 4; ++r) {
                    const float* ar = arow0 + (size_t)r * (NH * LL) + j0 + j4 * 4;
                    acc[r] = fmaf(ar[0], bv0, acc[r]);
                    acc[r] = fmaf(ar[1], bv1, acc[r]);
                    acc[r] = fmaf(ar[2], bv2, acc[r]);
                    acc[r] = fmaf(ar[3], bv3, acc[r]);
                }
            }
        }
    }
    if (n < 56) {
        if (n < 32) {
#pragma unroll
            for (int r = 0; r < 4; ++r) {
                int i = i0 + wv * 4 + r;
                feat[(size_t)i * DOUT + 768 + h * 32 + n] = acc[r];
            }
        } else {
#pragma unroll
            for (int r = 0; r < 4; ++r)
                sa[wv * 4 + r][n - 32] = acc[r];
        }
    }
    __syncthreads();
    // frame transform for this block's 16 rows x 8 points
    if (tid < 128) {
        const int ri = tid >> 3, p = tid & 7;
        const int i = i0 + ri;
        const int pt = h * 8 + p;
        float a0 = sa[ri][p*3+0], a1 = sa[ri][p*3+1], a2 = sa[ri][p*3+2];
        float d0 = a0 - t[i*3+0], d1 = a1 - t[i*3+1], d2 = a2 - t[i*3+2];
        float f0 = R[i*9+0]*d0 + R[i*9+3]*d1 + R[i*9+6]*d2;
        float f1 = R[i*9+1]*d0 + R[i*9+4]*d1 + R[i*9+7]*d2;
        float f2 = R[i*9+2]*d0 + R[i*9+5]*d1 + R[i*9+8]*d2;
        float dist = sqrtf(f0*f0 + f1*f1 + f2*f2);
        float inv = 1.f / (dist + 1e-4f);
        float* fr = feat + (size_t)i * DOUT;
        fr[1152 + pt*3+0] = f0; fr[1152 + pt*3+1] = f1; fr[1152 + pt*3+2] = f2;
        fr[1440 + pt] = dist;
        fr[1536 + pt*3+0] = f0*inv; fr[1536 + pt*3+1] = f1*inv; fr[1536 + pt*3+2] = f2*inv;
    }
}

// ---------------- K5a: out-projection split-K GEMM ----------------
// grid (12 mt, 12 ks), 512 thr. M-tile 32, N=128, K-slice 152. thread = 2 rows x 4 cols.
__global__ void __launch_bounds__(512) k5a_outproj(
    const float* __restrict__ feat, const float* __restrict__ Wout,
    float* __restrict__ partial) {
    const int mt = blockIdx.x, ks = blockIdx.y, tid = threadIdx.x;
    __shared__ float As[32 * 153];
    const int m0 = mt * 32, k0 = ks * 152;

    for (int idx = tid; idx < 32 * 38; idx += 512) {
        int r = idx / 38, c4 = idx % 38;
        float4 v = *(const float4*)&feat[(size_t)(m0 + r) * DOUT + k0 + c4 * 4];
        float* d = &As[r * 153 + c4 * 4];
        d[0] = v.x; d[1] = v.y; d[2] = v.z; d[3] = v.w;
    }
    __syncthreads();

    const int f0 = (tid & 31) * 4;
    const int r0 = (tid >> 5) * 2;
    const float* ar0 = &As[r0 * 153];
    const float* ar1 = &As[(r0 + 1) * 153];
    const float* wp = Wout + (size_t)k0 * FF + f0;
    float a00=0,a01=0,a02=0,a03=0, a10=0,a11=0,a12=0,a13=0;
#pragma unroll 4
    for (int k = 0; k < 152; ++k) {
        float4 w = *(const float4*)(wp + (size_t)k * FF);
        float xa = ar0[k], xb = ar1[k];
        a00 = fmaf(xa, w.x, a00); a01 = fmaf(xa, w.y, a01);
        a02 = fmaf(xa, w.z, a02); a03 = fmaf(xa, w.w, a03);
        a10 = fmaf(xb, w.x, a10); a11 = fmaf(xb, w.y, a11);
        a12 = fmaf(xb, w.z, a12); a13 = fmaf(xb, w.w, a13);
    }
    float* o0 = partial + ((size_t)ks * LL + m0 + r0) * FF + f0;
    *(float4*)o0 = make_float4(a00, a01, a02, a03);
    *(float4*)(o0 + FF) = make_float4(a10, a11, a12, a13);
}

// ---------------- K5b: per-row LN1 + MLP + LN2. grid 384, 256 thr ----------------
__global__ void __launch_bounds__(256) k5b_rowepi(
    const float* __restrict__ partial, const float* __restrict__ bout,
    const float* __restrict__ x,
    const float* __restrict__ ln1g, const float* __restrict__ ln1b,
    const float* __restrict__ W1, const float* __restrict__ b1,
    const float* __restrict__ W2, const float* __restrict__ b2,
    const float* __restrict__ W3, const float* __restrict__ b3,
    const float* __restrict__ ln2g, const float* __restrict__ ln2b,
    float* __restrict__ out) {
    const int i = blockIdx.x, tid = threadIdx.x;
    const int f = tid & 127, half = tid >> 7;
    __shared__ float prt[2][128];
    __shared__ float x1s[128], hbA[128], hbB[128];
    __shared__ float wrA[2], wrB[2];

    // reduce split-K partials (half 0: ks 0..5, half 1: ks 6..11)
    {
        float acc = 0.f;
#pragma unroll
        for (int k = 0; k < 6; ++k)
            acc += partial[((size_t)(half * 6 + k) * LL + i) * FF + f];
        prt[half][f] = acc;
    }
    __syncthreads();

    float s1 = 0.f, dv1 = 0.f;
    if (tid < 128) {
        s1 = prt[0][f] + prt[1][f] + bout[f] + x[(size_t)i * FF + f];
        float r = s1;
#pragma unroll
        for (int off = 32; off; off >>= 1) r += __shfl_xor(r, off);
        if ((tid & 63) == 0) wrA[tid >> 6] = r;
    }
    __syncthreads();
    if (tid < 128) {
        float mu = (wrA[0] + wrA[1]) * (1.f / FF);
        dv1 = s1 - mu;
        float r = dv1 * dv1;
#pragma unroll
        for (int off = 32; off; off >>= 1) r += __shfl_xor(r, off);
        if ((tid & 63) == 0) wrB[tid >> 6] = r;
    }
    __syncthreads();
    if (tid < 128) {
        float var = (wrB[0] + wrB[1]) * (1.f / FF);
        x1s[f] = dv1 * rsqrtf(var + 1e-5f) * ln1g[f] + ln1b[f];
    }
    __syncthreads();

    // MLP L1 (split-K=2)
    {
        float p0=0,p1=0,p2=0,p3=0;
        const int k0 = half * 64;
        for (int k = 0; k < 16; ++k) {
            int d = k0 + k * 4;
            p0 = fmaf(x1s[d+0], W1[(size_t)(d+0)*FF + f], p0);
            p1 = fmaf(x1s[d+1], W1[(size_t)(d+1)*FF + f], p1);
            p2 = fmaf(x1s[d+2], W1[(size_t)(d+2)*FF + f], p2);
            p3 = fmaf(x1s[d+3], W1[(size_t)(d+3)*FF + f], p3);
        }
        prt[half][f] = p0 + p1 + p2 + p3;
    }
    __syncthreads();
    if (tid < 128) hbA[f] = fmaxf(prt[0][f] + prt[1][f] + b1[f], 0.f);
    __syncthreads();
    // L2
    {
        float p0=0,p1=0,p2=0,p3=0;
        const int k0 = half * 64;
        for (int k = 0; k < 16; ++k) {
            int d = k0 + k * 4;
            p0 = fmaf(hbA[d+0], W2[(size_t)(d+0)*FF + f], p0);
            p1 = fmaf(hbA[d+1], W2[(size_t)(d+1)*FF + f], p1);
            p2 = fmaf(hbA[d+2], W2[(size_t)(d+2)*FF + f], p2);
            p3 = fmaf(hbA[d+3], W2[(size_t)(d+3)*FF + f], p3);
        }
        prt[half][f] = p0 + p1 + p2 + p3;
    }
    __syncthreads();
    if (tid < 128) hbB[f] = fmaxf(prt[0][f] + prt[1][f] + b2[f], 0.f);
    __syncthreads();
    // L3
    {
        float p0=0,p1=0,p2=0,p3=0;
        const int k0 = half * 64;
        for (int k = 0; k < 16; ++k) {
            int d = k0 + k * 4;
            p0 = fmaf(hbB[d+0], W3[(size_t)(d+0)*FF + f], p0);
            p1 = fmaf(hbB[d+1], W3[(size_t)(d+1)*FF + f], p1);
            p2 = fmaf(hbB[d+2], W3[(size_t)(d+2)*FF + f], p2);
            p3 = fmaf(hbB[d+3], W3[(size_t)(d+3)*FF + f], p3);
        }
        prt[half][f] = p0 + p1 + p2 + p3;
    }
    __syncthreads();

    float s2 = 0.f, dv2 = 0.f;
    if (tid < 128) {
        s2 = x1s[f] + prt[0][f] + prt[1][f] + b3[f];
        float r = s2;
#pragma unroll
        for (int off = 32; off; off >>= 1) r += __shfl_xor(r, off);
        if ((tid & 63) == 0) wrA[tid >> 6] = r;
    }
    __syncthreads();
    if (tid < 128) {
        float mu = (wrA[0] + wrA[1]) * (1.f / FF);
        dv2 = s2 - mu;
        float r = dv2 * dv2;
#pragma unroll
        for (int off = 32; off; off >>= 1) r += __shfl_xor(r, off);
        if ((tid & 63) == 0) wrB[tid >> 6] = r;
    }
    __syncthreads();
    if (tid < 128) {
        float var = (wrB[0] + wrB[1]) * (1.f / FF);
        out[(size_t)i * FF + f] = dv2 * rsqrtf(var + 1e-5f) * ln2g[f] + ln2b[f];
    }
}

extern "C" void kernel_launch(void* const* d_in, const int* in_sizes, int n_in,
                              void* d_out, int out_size, void* d_ws, size_t ws_size,
                              hipStream_t stream) {
    const float* R    = (const float*)d_in[0];
    const float* t    = (const float*)d_in[1];
    const float* x    = (const float*)d_in[2];
    const float* z    = (const float*)d_in[3];
    const float* Wq   = (const float*)d_in[5];
    const float* Wk   = (const float*)d_in[6];
    const float* Wv   = (const float*)d_in[7];
    const float* Wpb  = (const float*)d_in[8];
    const float* spc  = (const float*)d_in[9];
    const float* Wqp  = (const float*)d_in[10];
    const float* Wkp  = (const float*)d_in[11];
    const float* Wvp  = (const float*)d_in[12];
    const float* Wout = (const float*)d_in[13];
    const float* bout = (const float*)d_in[14];
    const float* ln1g = (const float*)d_in[15];
    const float* ln1b = (const float*)d_in[16];
    const float* W1   = (const float*)d_in[17];
    const float* b1   = (const float*)d_in[18];
    const float* W2   = (const float*)d_in[19];
    const float* b2   = (const float*)d_in[20];
    const float* W3   = (const float*)d_in[21];
    const float* b3   = (const float*)d_in[22];
    const float* ln2g = (const float*)d_in[23];
    const float* ln2b = (const float*)d_in[24];
    float* out = (float*)d_out;

    float* ws = (float*)d_ws;
    float* qb   = ws;
    float* kb   = qb   + (size_t)LL * HQK;
    float* vb   = kb   + (size_t)LL * HQK;
    float* qp   = vb   + (size_t)LL * HV;
    float* kp   = qp   + (size_t)LL * HP3;
    float* vp   = kp   + (size_t)LL * HP3;
    float* qnb  = vp   + (size_t)LL * HP3;
    float* knb  = qnb  + (size_t)LL * NH;
    float* lgA  = knb  + (size_t)LL * NH;        // [384][12][384] logits -> alpha
    float* feat = lgA  + (size_t)LL * NH * LL;   // [384][1824]
    float* part = feat + (size_t)LL * DOUT;      // [12][384][128]

    k1a_gemm<<<dim3(63, 6), 256, 0, stream>>>(x, Wq, Wk, Wv, Wqp, Wkp, Wvp,
                                              qb, kb, vb, qp, kp, vp);
    k1b_derived<<<LL, 128, 0, stream>>>(R, t, qp, kp, vp, qnb, knb);
    k3_node<<<dim3(6, 6, 12), 256, 0, stream>>>(qb, kb, qp, kp, qnb, knb, spc, lgA);
    k4a_fused<<<LL, 512, 0, stream>>>(z, Wpb, lgA, feat);
    k4b_aggr<<<dim3(24, 12), 256, 0, stream>>>(lgA, vb, vp, R, t, feat);
    k5a_outproj<<<dim3(12, 12), 512, 0, stream>>>(feat, Wout, part);
    k5b_rowepi<<<LL, 256, 0, stream>>>(part, bout, x, ln1g, ln1b,
                                       W1, b1, W2, b2, W3, b3, ln2g, ln2b, out);
}